// Round 6
// baseline (553.114 us; speedup 1.0000x reference)
//
#include <hip/hip_runtime.h>

// SpectralGNNEncoder on MI355X.
// out = (mu, logvar):
//   h1 = relu(Agg1(x@W1) + b1)   (sym-norm scatter-add w/ self loops)
//   g  = mean(Agg2(h1@W2)) + b2 = ((1/N) c^T h1) @ W2 + b2,  c[i]=dinv[i]^2+sum_{src=i} norm
// Round 6: k_fill split into fillA (block-local radix partition of (pos,val) records
// by pos/200000 shard, coalesced staging dump) + fillB (XCD-preferenced, cursor-driven
// scatter into 800KB L2-resident windows). k_agg edge-load software-pipelined.

typedef __bf16 bf16x8 __attribute__((ext_vector_type(8)));
typedef float f32x4 __attribute__((ext_vector_type(4)));
typedef float f32x2 __attribute__((ext_vector_type(2)));
typedef unsigned long long u64;

__device__ __forceinline__ float bf2f(unsigned short u){
  return __uint_as_float(((unsigned)u) << 16);
}
__device__ __forceinline__ unsigned short f2bf(float f){
  unsigned u = __float_as_uint(f);
  u += 0x7fffu + ((u >> 16) & 1u);   // RNE
  return (unsigned short)(u >> 16);
}
__device__ __forceinline__ __bf16 us2bf(unsigned short u){
  __bf16 b; __builtin_memcpy(&b, &u, 2); return b;
}
__device__ __forceinline__ float ldf(const void* p, int i, int isf32){
  return isf32 ? ((const float*)p)[i] : bf2f(((const unsigned short*)p)[i]);
}
// fma 8 fp8 feats (packed in uint2) into acc[8]
__device__ __forceinline__ void fma8f8(float* acc, float n, uint2 h){
  f32x2 p0 = __builtin_amdgcn_cvt_pk_f32_fp8((int)h.x, false);
  f32x2 p1 = __builtin_amdgcn_cvt_pk_f32_fp8((int)h.x, true);
  f32x2 p2 = __builtin_amdgcn_cvt_pk_f32_fp8((int)h.y, false);
  f32x2 p3 = __builtin_amdgcn_cvt_pk_f32_fp8((int)h.y, true);
  acc[0] = fmaf(n, p0[0], acc[0]);
  acc[1] = fmaf(n, p0[1], acc[1]);
  acc[2] = fmaf(n, p1[0], acc[2]);
  acc[3] = fmaf(n, p1[1], acc[3]);
  acc[4] = fmaf(n, p2[0], acc[4]);
  acc[5] = fmaf(n, p2[1], acc[5]);
  acc[6] = fmaf(n, p3[0], acc[6]);
  acc[7] = fmaf(n, p3[1], acc[7]);
}

// ---------- dtype sniffer: flag=1 iff float tensors are f32 ----------
__global__ void k_detect(const unsigned* __restrict__ xw, int* __restrict__ flag){
  __shared__ int s[256];
  int t = threadIdx.x;
  int cnt = 0;
  for (int i = t; i < 4096; i += 256){
    unsigned lo = xw[i] & 0xFFFFu;
    int e = (int)((lo >> 7) & 0xFFu);
    if ((e >= 100 && e <= 141) || (lo & 0x7FFFu) == 0) cnt++;
  }
  s[t] = cnt;
  __syncthreads();
  for (int off = 128; off > 0; off >>= 1){
    if (t < off) s[t] += s[t + off];
    __syncthreads();
  }
  if (t == 0) *flag = (s[0] < 2458) ? 1 : 0;
}

// ---------- init: zero shadowed accumulators + v + fillB cursors ----------
__global__ void k_init(u64* __restrict__ dc8, float* __restrict__ cfac8,
                       float* __restrict__ v, int* __restrict__ fbCur, int N){
  int i = blockIdx.x * 256 + threadIdx.x;
  if (i < N){
    #pragma unroll
    for (int b = 0; b < 8; ++b){
      dc8[(size_t)b * N + i] = 0ull;
      cfac8[(size_t)b * N + i] = 0.0f;
    }
  }
  if (i < 128) v[i] = 0.0f;
  if (i < 8)   fbCur[i] = 0;
}

// ---------- pass1: one u64 atomic = deg(fixed-point) + cnt; old>>40 = rank ----------
__global__ void k_pass1(const int* __restrict__ dst, const void* __restrict__ w,
                        u64* __restrict__ dc8, unsigned short* __restrict__ rank,
                        int E, int N, const int* __restrict__ flagp){
  int e = blockIdx.x * 256 + threadIdx.x;
  if (e >= E) return;
  int isf32 = *flagp;
  int d = dst[e];
  float wv = ldf(w, e, isf32);
  u64 wfix = (u64)(wv * 65536.0f + 0.5f);          // 2^-16 fixed point
  int b = blockIdx.x & 7;                          // shadow = (e>>8)&7
  u64 old = atomicAdd(&dc8[(size_t)b * N + d], (1ull << 40) | wfix);
  rank[e] = (unsigned short)(old >> 40);
}

// ---------- merge shadows: dinv, cnt, packed per-shadow prefix bytes ----------
__global__ void k_dinv(const u64* __restrict__ dc8, float* __restrict__ dinv,
                       int* __restrict__ cnt, u64* __restrict__ sbasePk, int N){
  int i = blockIdx.x * 256 + threadIdx.x;
  if (i >= N) return;
  unsigned sb = 0;
  u64 degfix = 0, pk = 0;
  #pragma unroll
  for (int b = 0; b < 8; ++b){
    u64 dcb = dc8[(size_t)b * N + i];
    pk |= ((u64)(sb & 0xFFu)) << (8 * b);          // exclusive prefix for shadow b
    sb += (unsigned)(dcb >> 40);
    degfix += dcb & 0xFFFFFFFFFFull;
  }
  float deg = 1.0f + (float)degfix * (1.0f / 65536.0f);  // +1 self loop
  dinv[i] = rsqrtf(deg);
  cnt[i] = (int)sb;
  sbasePk[i] = pk;
}

// ---------- exclusive scan of cnt -> rowptr ----------
__global__ void k_scanA(const int* __restrict__ cnt, int* __restrict__ rowptr,
                        int* __restrict__ bsum, int N){
  __shared__ int s[256];
  int i = blockIdx.x * 256 + threadIdx.x;
  int val = (i < N) ? cnt[i] : 0;
  s[threadIdx.x] = val;
  __syncthreads();
  for (int off = 1; off < 256; off <<= 1){
    int tmp = (threadIdx.x >= off) ? s[threadIdx.x - off] : 0;
    __syncthreads();
    s[threadIdx.x] += tmp;
    __syncthreads();
  }
  if (i < N) rowptr[i] = s[threadIdx.x] - val;
  if (threadIdx.x == 255) bsum[blockIdx.x] = s[255];
}

__global__ void k_scanB(const int* __restrict__ bsum, int* __restrict__ boffs, int NB){
  __shared__ int s[512];
  int t = threadIdx.x;
  int val = (t < NB) ? bsum[t] : 0;
  s[t] = val;
  __syncthreads();
  for (int off = 1; off < 512; off <<= 1){
    int tmp = (t >= off) ? s[t - off] : 0;
    __syncthreads();
    s[t] += tmp;
    __syncthreads();
  }
  boffs[t] = s[t] - val;
}

__global__ void k_scanC(int* __restrict__ rowptr, const int* __restrict__ boffs, int N){
  int i = blockIdx.x * 256 + threadIdx.x;
  if (i >= N) return;
  rowptr[i] += boffs[blockIdx.x];
}

// ---------- fillA: compute (pos,val) per edge, radix-partition by shard=pos/200000
// into block-local LDS groups, dump coalesced to staging + per-block histogram ----------
__global__ void __launch_bounds__(256) k_fillA(const int* __restrict__ src,
    const int* __restrict__ dst, const void* __restrict__ w,
    const float* __restrict__ dinv, const int* __restrict__ rowptr,
    const u64* __restrict__ sbasePk, const unsigned short* __restrict__ rank,
    uint2* __restrict__ stag, int* __restrict__ histE, float* __restrict__ cfac8,
    int E, int N, const int* __restrict__ flagp){
  __shared__ int gcnt[128];
  __shared__ int gincl[128];
  __shared__ uint2 buf[1024];
  int tid = threadIdx.x, lane = tid & 63, wv = tid >> 6;
  if (tid < 128) gcnt[tid] = 0;
  __syncthreads();
  int isf32 = *flagp;
  u64 ltmask = (1ull << lane) - 1ull;
  int shv[4], offv[4];
  unsigned posv[4], valv[4];
  #pragma unroll
  for (int k = 0; k < 4; ++k){
    int e = blockIdx.x * 1024 + k * 256 + tid;
    int sh = -1; unsigned pos = 0, val = 0;
    if (e < E){
      int s_ = src[e], d_ = dst[e];
      float nrm = dinv[s_] * ldf(w, e, isf32) * dinv[d_];
      int nq = (int)(nrm * 32768.0f + 0.5f);
      if (nq > 32767) nq = 32767;
      int b = (e >> 8) & 7;                        // MUST match k_pass1's shadow
      unsigned sb = (unsigned)((sbasePk[d_] >> (8 * b)) & 0xFFu);
      int p = rowptr[d_] + (int)sb + (int)rank[e];
      if (p >= E) p = E - 1;                       // safety clamp
      pos = (unsigned)p;
      val = ((unsigned)s_ << 15) | (unsigned)nq;
      sh = (int)(pos / 200000u);                   // shard: 800KB edges window
      atomicAdd(&cfac8[(size_t)b * N + s_], nrm);
    }
    int myoff = 0;
    #pragma unroll
    for (int s = 0; s < 8; ++s){
      u64 m = __ballot(sh == s);
      if (sh == s){
        myoff = __popcll(m & ltmask);
        if (myoff == 0) gcnt[s * 16 + k * 4 + wv] = __popcll(m);
      }
    }
    shv[k] = sh; offv[k] = myoff; posv[k] = pos; valv[k] = val;
  }
  __syncthreads();
  if (tid < 128) gincl[tid] = gcnt[tid];
  __syncthreads();
  for (int ofs = 1; ofs < 128; ofs <<= 1){
    int t2 = 0;
    if (tid < 128 && tid >= ofs) t2 = gincl[tid - ofs];
    __syncthreads();
    if (tid < 128) gincl[tid] += t2;
    __syncthreads();
  }
  #pragma unroll
  for (int k = 0; k < 4; ++k){
    if (shv[k] >= 0){
      int idx = shv[k] * 16 + k * 4 + wv;
      int base = gincl[idx] - gcnt[idx];
      buf[base + offv[k]] = make_uint2(posv[k], valv[k]);
    }
  }
  __syncthreads();
  int tot = gincl[127];
  for (int t = tid; t < tot; t += 256)
    stag[(size_t)blockIdx.x * 1024 + t] = buf[t];
  if (tid < 8){
    int a = gincl[tid * 16 + 15];
    int b2 = (tid > 0) ? gincl[tid * 16 - 1] : 0;
    histE[blockIdx.x * 8 + tid] = a - b2;
  }
}

// ---------- fillB: per-shard cursor-driven scatter into 800KB L2-local window ----------
__global__ void __launch_bounds__(256) k_fillB(const uint2* __restrict__ stag,
    const int* __restrict__ histE, int* __restrict__ fbCur,
    unsigned* __restrict__ edges, int NREG){
  __shared__ int claim;
  int tid = threadIdx.x, lane = tid & 63, wv = tid >> 6;
  for (int t = 0; t < 8; ++t){
    int s = ((int)blockIdx.x + t) & 7;             // XCD-preferenced, rotates for coverage
    while (true){
      if (tid == 0) claim = atomicAdd(&fbCur[s], 4);
      __syncthreads();
      int c = claim;
      __syncthreads();
      if (c >= NREG) break;
      int b = c + wv;
      if (b < NREG){
        int hv = (lane < 8) ? histE[b * 8 + lane] : 0;
        int off = 0, len = 0;
        #pragma unroll
        for (int i = 0; i < 8; ++i){
          int h = __shfl(hv, i);
          if (i < s) off += h;
          if (i == s) len = h;
        }
        const uint2* rp = stag + (size_t)b * 1024 + off;
        for (int i = lane; i < len; i += 64){
          uint2 r = rp[i];
          edges[r.x] = r.y;
        }
      }
    }
  }
}

// ---------- merge cfac shadows; pack per-node (dinv^2, cfac) and (rowptr, cnt) ----------
__global__ void k_cfacm(const float* __restrict__ cfac8, const float* __restrict__ dinv,
                        const int* __restrict__ rowptr, const int* __restrict__ cnt,
                        float2* __restrict__ dc, int2* __restrict__ rc, int N){
  int i = blockIdx.x * 256 + threadIdx.x;
  if (i >= N) return;
  float di = dinv[i];
  float c = di * di;
  #pragma unroll
  for (int b = 0; b < 8; ++b) c += cfac8[(size_t)b * N + i];
  dc[i] = make_float2(di * di, c);
  rc[i] = make_int2(rowptr[i], cnt[i]);
}

// ---------- W1T[n*128+k] = W1[k*128+n], canonical bf16 ----------
__global__ void k_transpose(const void* __restrict__ W1, unsigned short* __restrict__ W1T,
                            const int* __restrict__ flagp){
  int gid = blockIdx.x * 256 + threadIdx.x;
  int isf32 = *flagp;
  int k = gid & 127, n = gid >> 7;
  W1T[gid] = isf32 ? f2bf(((const float*)W1)[k * 128 + n])
                   : ((const unsigned short*)W1)[k * 128 + n];
}

// ---------- H = x @ W1 (bf16 MFMA); fp8 epilogue into 4 feature planes of 32 ----------
__global__ void __launch_bounds__(256) k_gemm(const void* __restrict__ xv,
                                              const __bf16* __restrict__ wt,
                                              unsigned char* __restrict__ H, int N,
                                              const int* __restrict__ flagp){
  int wave = (blockIdx.x * blockDim.x + threadIdx.x) >> 6;
  int lane = threadIdx.x & 63;
  int row16 = wave << 4;
  if (row16 >= N) return;
  int isf32 = *flagp;
  int m = lane & 15, q = lane >> 4;
  size_t planeStride = (size_t)N * 32;
  bf16x8 a0, a1, a2, a3;
  if (isf32){
    const float* ap = (const float*)xv + (size_t)(row16 + m) * 128 + q * 8;
    #pragma unroll
    for (int j = 0; j < 8; ++j){
      a0[j] = us2bf(f2bf(ap[j +  0]));
      a1[j] = us2bf(f2bf(ap[j + 32]));
      a2[j] = us2bf(f2bf(ap[j + 64]));
      a3[j] = us2bf(f2bf(ap[j + 96]));
    }
  } else {
    const __bf16* ap = (const __bf16*)xv + (size_t)(row16 + m) * 128 + q * 8;
    a0 = *(const bf16x8*)(ap +  0);
    a1 = *(const bf16x8*)(ap + 32);
    a2 = *(const bf16x8*)(ap + 64);
    a3 = *(const bf16x8*)(ap + 96);
  }
  for (int nt = 0; nt < 8; ++nt){
    const __bf16* bp = wt + (size_t)(nt * 16 + m) * 128 + q * 8;
    bf16x8 b0 = *(const bf16x8*)(bp +  0);
    bf16x8 b1 = *(const bf16x8*)(bp + 32);
    bf16x8 b2 = *(const bf16x8*)(bp + 64);
    bf16x8 b3 = *(const bf16x8*)(bp + 96);
    f32x4 acc = {0.f, 0.f, 0.f, 0.f};
    acc = __builtin_amdgcn_mfma_f32_16x16x32_bf16(a0, b0, acc, 0, 0, 0);
    acc = __builtin_amdgcn_mfma_f32_16x16x32_bf16(a1, b1, acc, 0, 0, 0);
    acc = __builtin_amdgcn_mfma_f32_16x16x32_bf16(a2, b2, acc, 0, 0, 0);
    acc = __builtin_amdgcn_mfma_f32_16x16x32_bf16(a3, b3, acc, 0, 0, 0);
    unsigned char* op = H + (size_t)(nt >> 1) * planeStride
                          + (size_t)(row16 + q * 4) * 32 + (nt & 1) * 16 + m;
    op[0]  = (unsigned char)(__builtin_amdgcn_cvt_pk_fp8_f32(acc[0], acc[0], 0, false) & 0xFF);
    op[32] = (unsigned char)(__builtin_amdgcn_cvt_pk_fp8_f32(acc[1], acc[1], 0, false) & 0xFF);
    op[64] = (unsigned char)(__builtin_amdgcn_cvt_pk_fp8_f32(acc[2], acc[2], 0, false) & 0xFF);
    op[96] = (unsigned char)(__builtin_amdgcn_cvt_pk_fp8_f32(acc[3], acc[3], 0, false) & 0xFF);
  }
}

// ---------- k_agg: XCD-sliced slot-parallel gather, edge-load software-pipelined ----------
__global__ void __launch_bounds__(256) k_agg(const unsigned char* __restrict__ H,
    const int2* __restrict__ rc, const float2* __restrict__ dc,
    const unsigned* __restrict__ edges, const void* __restrict__ b1,
    float* __restrict__ v, int N, int nblk, const int* __restrict__ flagp){
  __shared__ float vsh[32];
  int tid = threadIdx.x;
  if (tid < 32) vsh[tid] = 0.0f;
  __syncthreads();
  int isf32 = *flagp;
  int lane = tid & 63;
  int wv = tid >> 6;                  // wave in block 0..3
  int slot = lane >> 2;               // 0..15
  int q = lane & 3;                   // feature quarter within slice
  int sl = (blockIdx.x & 7) >> 1;     // slice/plane 0..3
  int jblk = (int)(blockIdx.x >> 3) * 2 + (blockIdx.x & 1);   // rank within slice
  int slotg = (jblk * 4 + wv) * 16 + slot;
  int totslots = (nblk >> 3) * 2 * 4 * 16;
  const unsigned char* Hp = H + (size_t)sl * ((size_t)N * 32);
  int fbase = sl * 32 + q * 8;
  float bx[8];
  #pragma unroll
  for (int j = 0; j < 8; ++j) bx[j] = ldf(b1, fbase + j, isf32);
  float ax[8] = {0,0,0,0,0,0,0,0};
  for (int d = slotg; d < N; d += totslots){
    int2  rcv = rc[d];                 // (rowptr, cnt)
    float2 dcv = dc[d];                // (dinv^2, cfac)
    float acc[8] = {0,0,0,0,0,0,0,0};
    uint2 hs = *(const uint2*)(Hp + (size_t)d * 32 + q * 8);
    fma8f8(acc, dcv.x, hs);            // self-loop term
    int p = rcv.x, pe = rcv.x + rcv.y;
    if (p < pe){
      unsigned r = edges[p];
      for (;;){
        unsigned rn = (p + 1 < pe) ? edges[p + 1] : 0u;   // prefetch next edge word
        uint2 h = *(const uint2*)(Hp + (size_t)(r >> 15) * 32 + q * 8);
        fma8f8(acc, (float)(r & 32767u) * (1.0f / 32768.0f), h);
        ++p;
        if (p >= pe) break;
        r = rn;
      }
    }
    #pragma unroll
    for (int j = 0; j < 8; ++j){
      float rj = fmaxf(acc[j] + bx[j], 0.0f);
      ax[j] = fmaf(dcv.y, rj, ax[j]);
    }
  }
  // cross-slot reduce (lane bits 2..5), once per wave
  #pragma unroll
  for (int j = 0; j < 8; ++j){
    ax[j] += __shfl_xor(ax[j], 4);
    ax[j] += __shfl_xor(ax[j], 8);
    ax[j] += __shfl_xor(ax[j], 16);
    ax[j] += __shfl_xor(ax[j], 32);
  }
  if (slot == 0){
    #pragma unroll
    for (int j = 0; j < 8; ++j) atomicAdd(&vsh[q * 8 + j], ax[j]);
  }
  __syncthreads();
  if (tid < 32) atomicAdd(&v[sl * 32 + tid], vsh[tid]);
}

// ---------- tiny head ----------
__global__ void __launch_bounds__(128) k_head(const float* __restrict__ v,
    const void* __restrict__ W2, const void* __restrict__ b2,
    const void* __restrict__ Wmu, const void* __restrict__ bmu,
    const void* __restrict__ Wlv, const void* __restrict__ blv,
    void* __restrict__ outv, float invN, const int* __restrict__ flagp){
  __shared__ float gsh[128];
  __shared__ float tsh[128];
  int t = threadIdx.x;
  int isf32 = *flagp;
  gsh[t] = v[t] * invN;
  __syncthreads();
  float acc = ldf(b2, t, isf32);
  for (int k = 0; k < 128; ++k) acc = fmaf(gsh[k], ldf(W2, k * 128 + t, isf32), acc);
  tsh[t] = acc;
  __syncthreads();
  int j = t & 63;
  const void* Wp = (t < 64) ? Wmu : Wlv;
  float o = ldf((t < 64) ? bmu : blv, j, isf32);
  for (int k = 0; k < 128; ++k) o = fmaf(tsh[k], ldf(Wp, k * 64 + j, isf32), o);
  if (isf32) ((float*)outv)[t] = o;
  else       ((unsigned short*)outv)[t] = f2bf(o);
}

extern "C" void kernel_launch(void* const* d_in, const int* in_sizes, int n_in,
                              void* d_out, int out_size, void* d_ws, size_t ws_size,
                              hipStream_t stream) {
  const void* x   = d_in[0];
  const int*  ei  = (const int*)d_in[1];
  const void* w   = d_in[2];
  const void* W1  = d_in[3];
  const void* b1  = d_in[4];
  const void* W2  = d_in[5];
  const void* b2  = d_in[6];
  const void* Wmu = d_in[7];
  const void* bmu = d_in[8];
  const void* Wlv = d_in[9];
  const void* blv = d_in[10];

  const int N = in_sizes[0] / 128;     // 100000
  const int E = in_sizes[2];           // 1600000
  const int* src = ei;
  const int* dst = ei + E;

  char* wsb = (char*)d_ws;
  size_t off = 0;
  auto alloc = [&](size_t bytes) -> void* {
    off = (off + 255) & ~(size_t)255;
    void* p = wsb + off;
    off += bytes;
    return p;
  };
  const int NREG = (E + 1023) / 1024;  // 1563 staging regions
  int*   flag     = (int*)  alloc(16);
  float* dinv     = (float*)alloc((size_t)N * 4);
  int*   cnt      = (int*)  alloc((size_t)N * 4);
  int*   rowptr   = (int*)  alloc((size_t)(N + 1) * 4);
  u64*   sbasePk  = (u64*)  alloc((size_t)N * 8);
  float2* dc      = (float2*)alloc((size_t)N * 8);
  int2*   rc      = (int2*) alloc((size_t)N * 8);
  int*   bsum     = (int*)  alloc(512 * 4);
  int*   boffs    = (int*)  alloc(512 * 4);
  float* v        = (float*)alloc(128 * 4);
  int*   fbCur    = (int*)  alloc(32);
  int*   histE    = (int*)  alloc((size_t)NREG * 8 * 4);
  unsigned short* W1T = (unsigned short*)alloc(128 * 128 * 2);
  float* cfac8    = (float*)alloc((size_t)N * 8 * 4);
  unsigned* edges = (unsigned*)alloc((size_t)E * 4);
  // regionA: {dc8 (N*8*8, dead after k_dinv) | rank (E*2, dead after fillA)}
  char* regionA = (char*)alloc((size_t)N * 8 * 8 + (size_t)E * 2);
  u64*            dc8  = (u64*)regionA;
  unsigned short* rank = (unsigned short*)(regionA + (size_t)N * 8 * 8);
  // regionB: stag (NREG*1024*8, dead after fillB) overlaid by H (N*128, from k_gemm)
  size_t stag_b = (size_t)NREG * 1024 * 8;
  size_t H_b    = (size_t)N * 128;
  char* regionB = (char*)alloc(stag_b > H_b ? stag_b : H_b);
  uint2*         stag = (uint2*)regionB;
  unsigned char* H    = (unsigned char*)regionB;
  (void)ws_size; (void)n_in; (void)out_size;

  const int nb_n = (N + 255) / 256;    // 391
  const int nb_e = (E + 255) / 256;    // 6250

  k_detect<<<1, 256, 0, stream>>>((const unsigned*)x, flag);
  k_init<<<nb_n, 256, 0, stream>>>(dc8, cfac8, v, fbCur, N);
  k_pass1<<<nb_e, 256, 0, stream>>>(dst, w, dc8, rank, E, N, flag);
  k_dinv<<<nb_n, 256, 0, stream>>>(dc8, dinv, cnt, sbasePk, N);
  k_scanA<<<nb_n, 256, 0, stream>>>(cnt, rowptr, bsum, N);
  k_scanB<<<1, 512, 0, stream>>>(bsum, boffs, nb_n);
  k_scanC<<<nb_n, 256, 0, stream>>>(rowptr, boffs, N);
  k_fillA<<<NREG, 256, 0, stream>>>(src, dst, w, dinv, rowptr, sbasePk, rank,
                                    stag, histE, cfac8, E, N, flag);
  k_fillB<<<1024, 256, 0, stream>>>(stag, histE, fbCur, edges, NREG);
  k_cfacm<<<nb_n, 256, 0, stream>>>(cfac8, dinv, rowptr, cnt, dc, rc, N);
  k_transpose<<<64, 256, 0, stream>>>(W1, W1T, flag);
  const int nwaves = (N + 15) / 16;
  const int nb_g = (nwaves + 3) / 4;
  k_gemm<<<nb_g, 256, 0, stream>>>(x, (const __bf16*)W1T, H, N, flag);
  const int nb_agg = 2048;
  k_agg<<<nb_agg, 256, 0, stream>>>(H, rc, dc, edges, b1, v, N, nb_agg, flag);
  k_head<<<1, 128, 0, stream>>>(v, W2, b2, Wmu, bmu, Wlv, blv,
                                d_out, 1.0f / (float)N, flag);
}

// Round 7
// 412.748 us; speedup vs baseline: 1.3401x; 1.3401x over previous
//
#include <hip/hip_runtime.h>

// SpectralGNNEncoder on MI355X.
// out = (mu, logvar):
//   h1 = relu(Agg1(x@W1) + b1)   (sym-norm scatter-add w/ self loops)
//   g  = mean(Agg2(h1@W2)) + b2 = ((1/N) c^T h1) @ W2 + b2,  c[i]=dinv[i]^2+dinv[i]*S[i]
// Round 7: static fillB (no cursor spin), slim fillA (one 16B nodeF read/edge,
// XCD-local cfac atomics), H' = 8*dinv*h fp8 (edges carry (src,w)), pass1 4-way ILP,
// agg 2-deep load pipeline.

typedef __bf16 bf16x8 __attribute__((ext_vector_type(8)));
typedef float f32x4 __attribute__((ext_vector_type(4)));
typedef float f32x2 __attribute__((ext_vector_type(2)));
typedef unsigned long long u64;

__device__ __forceinline__ float bf2f(unsigned short u){
  return __uint_as_float(((unsigned)u) << 16);
}
__device__ __forceinline__ unsigned short f2bf(float f){
  unsigned u = __float_as_uint(f);
  u += 0x7fffu + ((u >> 16) & 1u);   // RNE
  return (unsigned short)(u >> 16);
}
__device__ __forceinline__ __bf16 us2bf(unsigned short u){
  __bf16 b; __builtin_memcpy(&b, &u, 2); return b;
}
__device__ __forceinline__ float ldf(const void* p, int i, int isf32){
  return isf32 ? ((const float*)p)[i] : bf2f(((const unsigned short*)p)[i]);
}
// fma 8 fp8 feats (packed in uint2) into acc[8]
__device__ __forceinline__ void fma8f8(float* acc, float n, uint2 h){
  f32x2 p0 = __builtin_amdgcn_cvt_pk_f32_fp8((int)h.x, false);
  f32x2 p1 = __builtin_amdgcn_cvt_pk_f32_fp8((int)h.x, true);
  f32x2 p2 = __builtin_amdgcn_cvt_pk_f32_fp8((int)h.y, false);
  f32x2 p3 = __builtin_amdgcn_cvt_pk_f32_fp8((int)h.y, true);
  acc[0] = fmaf(n, p0[0], acc[0]);
  acc[1] = fmaf(n, p0[1], acc[1]);
  acc[2] = fmaf(n, p1[0], acc[2]);
  acc[3] = fmaf(n, p1[1], acc[3]);
  acc[4] = fmaf(n, p2[0], acc[4]);
  acc[5] = fmaf(n, p2[1], acc[5]);
  acc[6] = fmaf(n, p3[0], acc[6]);
  acc[7] = fmaf(n, p3[1], acc[7]);
}

// ---------- init (+ dtype sniff in block 0): flag=1 iff float tensors are f32 ----------
__global__ void k_init(const unsigned* __restrict__ xw, int* __restrict__ flag,
                       u64* __restrict__ dc8, float* __restrict__ cfac8,
                       float* __restrict__ v, int N){
  int i = blockIdx.x * 256 + threadIdx.x;
  if (i < N){
    #pragma unroll
    for (int b = 0; b < 8; ++b){
      dc8[(size_t)b * N + i] = 0ull;
      cfac8[(size_t)b * N + i] = 0.0f;
    }
  }
  if (i < 128) v[i] = 0.0f;
  if (blockIdx.x == 0){
    __shared__ int s[256];
    int t = threadIdx.x;
    int cnt = 0;
    for (int k = t; k < 4096; k += 256){
      unsigned lo = xw[k] & 0xFFFFu;
      int e = (int)((lo >> 7) & 0xFFu);
      if ((e >= 100 && e <= 141) || (lo & 0x7FFFu) == 0) cnt++;
    }
    s[t] = cnt;
    __syncthreads();
    for (int off = 128; off > 0; off >>= 1){
      if (t < off) s[t] += s[t + off];
      __syncthreads();
    }
    if (t == 0) *flag = (s[0] < 2458) ? 1 : 0;
  }
}

// ---------- pass1: u64 atomic = deg(fixed)|cnt, rank from old; 4 edges/thread ----------
__global__ void __launch_bounds__(256) k_pass1(const int* __restrict__ dst,
                        const void* __restrict__ w,
                        u64* __restrict__ dc8, unsigned short* __restrict__ rank,
                        int E, int N, const int* __restrict__ flagp){
  int isf32 = *flagp;
  int tid = threadIdx.x;
  int ev[4]; int dv[4]; float wv[4];
  #pragma unroll
  for (int k = 0; k < 4; ++k){
    int e = blockIdx.x * 1024 + k * 256 + tid;
    ev[k] = e;
    dv[k] = (e < E) ? dst[e] : 0;
    wv[k] = (e < E) ? ldf(w, e, isf32) : 0.0f;
  }
  u64 old[4];
  #pragma unroll
  for (int k = 0; k < 4; ++k){
    if (ev[k] < E){
      u64 wfix = (u64)(wv[k] * 65536.0f + 0.5f);
      int b = (ev[k] >> 8) & 7;                    // shadow keyed by edge block-of-256
      old[k] = atomicAdd(&dc8[(size_t)b * N + dv[k]], (1ull << 40) | wfix);
    }
  }
  #pragma unroll
  for (int k = 0; k < 4; ++k)
    if (ev[k] < E) rank[ev[k]] = (unsigned short)(old[k] >> 40);
}

// ---------- merge shadows: dinv, cnt, packed per-shadow prefix bytes ----------
__global__ void k_dinv(const u64* __restrict__ dc8, float* __restrict__ dinv,
                       int* __restrict__ cnt, u64* __restrict__ sbasePk, int N){
  int i = blockIdx.x * 256 + threadIdx.x;
  if (i >= N) return;
  unsigned sb = 0;
  u64 degfix = 0, pk = 0;
  #pragma unroll
  for (int b = 0; b < 8; ++b){
    u64 dcb = dc8[(size_t)b * N + i];
    pk |= ((u64)(sb & 0xFFu)) << (8 * b);          // exclusive prefix for shadow b
    sb += (unsigned)(dcb >> 40);
    degfix += dcb & 0xFFFFFFFFFFull;
  }
  float deg = 1.0f + (float)degfix * (1.0f / 65536.0f);  // +1 self loop
  dinv[i] = rsqrtf(deg);
  cnt[i] = (int)sb;
  sbasePk[i] = pk;
}

// ---------- exclusive scan of cnt -> rowptr ----------
__global__ void k_scanA(const int* __restrict__ cnt, int* __restrict__ rowptr,
                        int* __restrict__ bsum, int N){
  __shared__ int s[256];
  int i = blockIdx.x * 256 + threadIdx.x;
  int val = (i < N) ? cnt[i] : 0;
  s[threadIdx.x] = val;
  __syncthreads();
  for (int off = 1; off < 256; off <<= 1){
    int tmp = (threadIdx.x >= off) ? s[threadIdx.x - off] : 0;
    __syncthreads();
    s[threadIdx.x] += tmp;
    __syncthreads();
  }
  if (i < N) rowptr[i] = s[threadIdx.x] - val;
  if (threadIdx.x == 255) bsum[blockIdx.x] = s[255];
}

__global__ void k_scanB(const int* __restrict__ bsum, int* __restrict__ boffs, int NB){
  __shared__ int s[512];
  int t = threadIdx.x;
  int val = (t < NB) ? bsum[t] : 0;
  s[t] = val;
  __syncthreads();
  for (int off = 1; off < 512; off <<= 1){
    int tmp = (t >= off) ? s[t - off] : 0;
    __syncthreads();
    s[t] += tmp;
    __syncthreads();
  }
  boffs[t] = s[t] - val;
}

// ---------- scanC: finalize rowptr AND build nodeF = {sbasePk(8B), rowptr(4B), dinv(4B)} ----------
__global__ void k_scanC(int* __restrict__ rowptr, const int* __restrict__ boffs,
                        const u64* __restrict__ sbasePk, const float* __restrict__ dinv,
                        uint4* __restrict__ nodeF, int N){
  int i = blockIdx.x * 256 + threadIdx.x;
  if (i >= N) return;
  int rp = rowptr[i] + boffs[blockIdx.x];
  rowptr[i] = rp;
  u64 pk = sbasePk[i];
  uint4 nf;
  nf.x = (unsigned)(pk & 0xFFFFFFFFull);
  nf.y = (unsigned)(pk >> 32);
  nf.z = (unsigned)rp;
  nf.w = __float_as_uint(dinv[i]);
  nodeF[i] = nf;
}

// ---------- fillA: one 16B nodeF read/edge; radix-partition (pos,val) records by
// shard=pos/SHSZ into LDS; coalesced staging dump + histogram; XCD-local cfac ----------
__global__ void __launch_bounds__(256) k_fillA(const int* __restrict__ src,
    const int* __restrict__ dst, const void* __restrict__ w,
    const uint4* __restrict__ nodeF, const unsigned short* __restrict__ rank,
    uint2* __restrict__ stag, int* __restrict__ histE, float* __restrict__ cfac8,
    int E, int N, int SHSZ, const int* __restrict__ flagp){
  __shared__ int gcnt[128];
  __shared__ int gincl[128];
  __shared__ uint2 buf[1024];
  int tid = threadIdx.x, lane = tid & 63, wv = tid >> 6;
  if (tid < 128) gcnt[tid] = 0;
  __syncthreads();
  int isf32 = *flagp;
  u64 ltmask = (1ull << lane) - 1ull;
  int sv[4]; float wq[4]; int rk[4]; int ev[4];
  uint4 nf[4];
  #pragma unroll
  for (int k = 0; k < 4; ++k){
    int e = blockIdx.x * 1024 + k * 256 + tid;
    ev[k] = e;
    int d_ = 0;
    if (e < E){
      sv[k] = src[e];
      d_    = dst[e];
      wq[k] = ldf(w, e, isf32);
      rk[k] = rank[e];
    }
    nf[k] = nodeF[d_];                             // 4 independent 16B random reads
  }
  int shv[4], offv[4];
  unsigned posv[4], valv[4];
  float cfv[4];
  #pragma unroll
  for (int k = 0; k < 4; ++k){
    int sh = -1; unsigned pos = 0, val = 0; cfv[k] = 0.0f;
    if (ev[k] < E){
      int b = (ev[k] >> 8) & 7;                    // MUST match k_pass1's shadow
      u64 pk = ((u64)nf[k].y << 32) | nf[k].x;
      unsigned sb = (unsigned)((pk >> (8 * b)) & 0xFFu);
      int p = (int)nf[k].z + (int)sb + rk[k];
      if (p >= E) p = E - 1;                       // safety clamp
      int nq = (int)(wq[k] * 32768.0f + 0.5f);
      if (nq > 32767) nq = 32767;
      pos = (unsigned)p;
      val = ((unsigned)sv[k] << 15) | (unsigned)nq;
      sh = (int)(pos / (unsigned)SHSZ);
      cfv[k] = wq[k] * __uint_as_float(nf[k].w);   // w_e * dinv_d
    }
    int myoff = 0;
    #pragma unroll
    for (int s = 0; s < 8; ++s){
      u64 m = __ballot(sh == s);
      if (sh == s){
        myoff = __popcll(m & ltmask);
        if (myoff == 0) gcnt[s * 16 + k * 4 + wv] = __popcll(m);
      }
    }
    shv[k] = sh; offv[k] = myoff; posv[k] = pos; valv[k] = val;
  }
  // cfac atomics: shadow = blockIdx&7 (XCD-local slab), keyed by src
  int cb = blockIdx.x & 7;
  #pragma unroll
  for (int k = 0; k < 4; ++k)
    if (ev[k] < E) atomicAdd(&cfac8[(size_t)cb * N + sv[k]], cfv[k]);
  __syncthreads();
  if (tid < 128) gincl[tid] = gcnt[tid];
  __syncthreads();
  for (int ofs = 1; ofs < 128; ofs <<= 1){
    int t2 = 0;
    if (tid < 128 && tid >= ofs) t2 = gincl[tid - ofs];
    __syncthreads();
    if (tid < 128) gincl[tid] += t2;
    __syncthreads();
  }
  #pragma unroll
  for (int k = 0; k < 4; ++k){
    if (shv[k] >= 0){
      int idx = shv[k] * 16 + k * 4 + wv;
      int base = gincl[idx] - gcnt[idx];
      buf[base + offv[k]] = make_uint2(posv[k], valv[k]);
    }
  }
  __syncthreads();
  int tot = gincl[127];
  for (int t = tid; t < tot; t += 256)
    stag[(size_t)blockIdx.x * 1024 + t] = buf[t];
  if (tid < 8){
    int a = gincl[tid * 16 + 15];
    int b2 = (tid > 0) ? gincl[tid * 16 - 1] : 0;
    histE[blockIdx.x * 8 + tid] = a - b2;
  }
}

// ---------- fillB: STATIC assignment. Block B -> shard s=B&7 (XCD-pinned),
// regions (B>>3)*4 + wave. No atomics, no spins. ----------
__global__ void __launch_bounds__(256) k_fillB(const uint2* __restrict__ stag,
    const int* __restrict__ histE, unsigned* __restrict__ edges, int NREG){
  int tid = threadIdx.x, lane = tid & 63, wv = tid >> 6;
  int s = (int)blockIdx.x & 7;
  int r = ((int)blockIdx.x >> 3) * 4 + wv;
  if (r >= NREG) return;
  int hv = (lane < 8) ? histE[r * 8 + lane] : 0;
  int off = 0, len = 0;
  #pragma unroll
  for (int i = 0; i < 8; ++i){
    int h = __shfl(hv, i);
    if (i < s) off += h;
    if (i == s) len = h;
  }
  const uint2* rp = stag + (size_t)r * 1024 + off;
  for (int i = lane; i < len; i += 64){
    uint2 rec = rp[i];
    edges[rec.x] = rec.y;                          // scatter into L2-local 800KB window
  }
}

// ---------- merge cfac shadows; pack (dinv, cfac) and (rowptr, cnt) ----------
__global__ void k_cfacm(const float* __restrict__ cfac8, const float* __restrict__ dinv,
                        const int* __restrict__ rowptr, const int* __restrict__ cnt,
                        float2* __restrict__ dc, int2* __restrict__ rc, int N){
  int i = blockIdx.x * 256 + threadIdx.x;
  if (i >= N) return;
  float di = dinv[i];
  float S = 0.0f;
  #pragma unroll
  for (int b = 0; b < 8; ++b) S += cfac8[(size_t)b * N + i];
  dc[i] = make_float2(di, di * di + di * S);       // (dinv, cfac)
  rc[i] = make_int2(rowptr[i], cnt[i]);
}

// ---------- W1T[n*128+k] = W1[k*128+n], canonical bf16 ----------
__global__ void k_transpose(const void* __restrict__ W1, unsigned short* __restrict__ W1T,
                            const int* __restrict__ flagp){
  int gid = blockIdx.x * 256 + threadIdx.x;
  int isf32 = *flagp;
  int k = gid & 127, n = gid >> 7;
  W1T[gid] = isf32 ? f2bf(((const float*)W1)[k * 128 + n])
                   : ((const unsigned short*)W1)[k * 128 + n];
}

// ---------- H' = 8*dinv_row*(x@W1) as fp8, 4 feature-planes of 32 ----------
__global__ void __launch_bounds__(256) k_gemm(const void* __restrict__ xv,
                                              const __bf16* __restrict__ wt,
                                              const float* __restrict__ dinv,
                                              unsigned char* __restrict__ H, int N,
                                              const int* __restrict__ flagp){
  int wave = (blockIdx.x * blockDim.x + threadIdx.x) >> 6;
  int lane = threadIdx.x & 63;
  int row16 = wave << 4;
  if (row16 >= N) return;
  int isf32 = *flagp;
  int m = lane & 15, q = lane >> 4;
  size_t planeStride = (size_t)N * 32;
  f32x4 dv;
  {
    const float4 d4 = *(const float4*)(dinv + row16 + q * 4);
    dv[0] = 8.0f * d4.x; dv[1] = 8.0f * d4.y; dv[2] = 8.0f * d4.z; dv[3] = 8.0f * d4.w;
  }
  bf16x8 a0, a1, a2, a3;
  if (isf32){
    const float* ap = (const float*)xv + (size_t)(row16 + m) * 128 + q * 8;
    #pragma unroll
    for (int j = 0; j < 8; ++j){
      a0[j] = us2bf(f2bf(ap[j +  0]));
      a1[j] = us2bf(f2bf(ap[j + 32]));
      a2[j] = us2bf(f2bf(ap[j + 64]));
      a3[j] = us2bf(f2bf(ap[j + 96]));
    }
  } else {
    const __bf16* ap = (const __bf16*)xv + (size_t)(row16 + m) * 128 + q * 8;
    a0 = *(const bf16x8*)(ap +  0);
    a1 = *(const bf16x8*)(ap + 32);
    a2 = *(const bf16x8*)(ap + 64);
    a3 = *(const bf16x8*)(ap + 96);
  }
  for (int nt = 0; nt < 8; ++nt){
    const __bf16* bp = wt + (size_t)(nt * 16 + m) * 128 + q * 8;
    bf16x8 b0 = *(const bf16x8*)(bp +  0);
    bf16x8 b1 = *(const bf16x8*)(bp + 32);
    bf16x8 b2 = *(const bf16x8*)(bp + 64);
    bf16x8 b3 = *(const bf16x8*)(bp + 96);
    f32x4 acc = {0.f, 0.f, 0.f, 0.f};
    acc = __builtin_amdgcn_mfma_f32_16x16x32_bf16(a0, b0, acc, 0, 0, 0);
    acc = __builtin_amdgcn_mfma_f32_16x16x32_bf16(a1, b1, acc, 0, 0, 0);
    acc = __builtin_amdgcn_mfma_f32_16x16x32_bf16(a2, b2, acc, 0, 0, 0);
    acc = __builtin_amdgcn_mfma_f32_16x16x32_bf16(a3, b3, acc, 0, 0, 0);
    unsigned char* op = H + (size_t)(nt >> 1) * planeStride
                          + (size_t)(row16 + q * 4) * 32 + (nt & 1) * 16 + m;
    float v0 = acc[0] * dv[0], v1 = acc[1] * dv[1];
    float v2 = acc[2] * dv[2], v3 = acc[3] * dv[3];
    op[0]  = (unsigned char)(__builtin_amdgcn_cvt_pk_fp8_f32(v0, v0, 0, false) & 0xFF);
    op[32] = (unsigned char)(__builtin_amdgcn_cvt_pk_fp8_f32(v1, v1, 0, false) & 0xFF);
    op[64] = (unsigned char)(__builtin_amdgcn_cvt_pk_fp8_f32(v2, v2, 0, false) & 0xFF);
    op[96] = (unsigned char)(__builtin_amdgcn_cvt_pk_fp8_f32(v3, v3, 0, false) & 0xFF);
  }
}

// ---------- k_agg: XCD-sliced slot-parallel gather; 2-deep pipeline (edge word
// AND H-gather of next edge in flight). y = dinv_d * acc / 8. ----------
__global__ void __launch_bounds__(256) k_agg(const unsigned char* __restrict__ H,
    const int2* __restrict__ rc, const float2* __restrict__ dc,
    const unsigned* __restrict__ edges, const void* __restrict__ b1,
    float* __restrict__ v, int N, int nblk, const int* __restrict__ flagp){
  __shared__ float vsh[32];
  int tid = threadIdx.x;
  if (tid < 32) vsh[tid] = 0.0f;
  __syncthreads();
  int isf32 = *flagp;
  int lane = tid & 63;
  int wv = tid >> 6;                  // wave in block 0..3
  int slot = lane >> 2;               // 0..15
  int q = lane & 3;                   // feature quarter within slice
  int sl = (blockIdx.x & 7) >> 1;     // slice/plane 0..3
  int jblk = (int)(blockIdx.x >> 3) * 2 + (blockIdx.x & 1);   // rank within slice
  int slotg = (jblk * 4 + wv) * 16 + slot;
  int totslots = (nblk >> 3) * 2 * 4 * 16;
  const unsigned char* Hp = H + (size_t)sl * ((size_t)N * 32);
  int fbase = sl * 32 + q * 8;
  float bx[8];
  #pragma unroll
  for (int j = 0; j < 8; ++j) bx[j] = ldf(b1, fbase + j, isf32);
  float ax[8] = {0,0,0,0,0,0,0,0};
  for (int d = slotg; d < N; d += totslots){
    int2  rcv = rc[d];                 // (rowptr, cnt)
    float2 dcv = dc[d];                // (dinv, cfac)
    float acc[8] = {0,0,0,0,0,0,0,0};
    uint2 hs = *(const uint2*)(Hp + (size_t)d * 32 + q * 8);
    fma8f8(acc, 1.0f, hs);             // self-loop: weight 1 in H' space
    int p = rcv.x, pe = rcv.x + rcv.y;
    if (p < pe){
      unsigned r = edges[p];
      uint2 h = *(const uint2*)(Hp + (size_t)(r >> 15) * 32 + q * 8);
      while (++p < pe){
        unsigned rn = edges[p];        // next edge word in flight
        uint2 hn = *(const uint2*)(Hp + (size_t)(rn >> 15) * 32 + q * 8);  // next gather
        fma8f8(acc, (float)(r & 32767u) * (1.0f / 32768.0f), h);
        r = rn; h = hn;
      }
      fma8f8(acc, (float)(r & 32767u) * (1.0f / 32768.0f), h);
    }
    float scale = dcv.x * 0.125f;      // dinv_d / 8
    #pragma unroll
    for (int j = 0; j < 8; ++j){
      float rj = fmaxf(fmaf(scale, acc[j], bx[j]), 0.0f);
      ax[j] = fmaf(dcv.y, rj, ax[j]);
    }
  }
  // cross-slot reduce (lane bits 2..5), once per wave
  #pragma unroll
  for (int j = 0; j < 8; ++j){
    ax[j] += __shfl_xor(ax[j], 4);
    ax[j] += __shfl_xor(ax[j], 8);
    ax[j] += __shfl_xor(ax[j], 16);
    ax[j] += __shfl_xor(ax[j], 32);
  }
  if (slot == 0){
    #pragma unroll
    for (int j = 0; j < 8; ++j) atomicAdd(&vsh[q * 8 + j], ax[j]);
  }
  __syncthreads();
  if (tid < 32) atomicAdd(&v[sl * 32 + tid], vsh[tid]);
}

// ---------- tiny head ----------
__global__ void __launch_bounds__(128) k_head(const float* __restrict__ v,
    const void* __restrict__ W2, const void* __restrict__ b2,
    const void* __restrict__ Wmu, const void* __restrict__ bmu,
    const void* __restrict__ Wlv, const void* __restrict__ blv,
    void* __restrict__ outv, float invN, const int* __restrict__ flagp){
  __shared__ float gsh[128];
  __shared__ float tsh[128];
  int t = threadIdx.x;
  int isf32 = *flagp;
  gsh[t] = v[t] * invN;
  __syncthreads();
  float acc = ldf(b2, t, isf32);
  for (int k = 0; k < 128; ++k) acc = fmaf(gsh[k], ldf(W2, k * 128 + t, isf32), acc);
  tsh[t] = acc;
  __syncthreads();
  int j = t & 63;
  const void* Wp = (t < 64) ? Wmu : Wlv;
  float o = ldf((t < 64) ? bmu : blv, j, isf32);
  for (int k = 0; k < 128; ++k) o = fmaf(tsh[k], ldf(Wp, k * 64 + j, isf32), o);
  if (isf32) ((float*)outv)[t] = o;
  else       ((unsigned short*)outv)[t] = f2bf(o);
}

extern "C" void kernel_launch(void* const* d_in, const int* in_sizes, int n_in,
                              void* d_out, int out_size, void* d_ws, size_t ws_size,
                              hipStream_t stream) {
  const void* x   = d_in[0];
  const int*  ei  = (const int*)d_in[1];
  const void* w   = d_in[2];
  const void* W1  = d_in[3];
  const void* b1  = d_in[4];
  const void* W2  = d_in[5];
  const void* b2  = d_in[6];
  const void* Wmu = d_in[7];
  const void* bmu = d_in[8];
  const void* Wlv = d_in[9];
  const void* blv = d_in[10];

  const int N = in_sizes[0] / 128;     // 100000
  const int E = in_sizes[2];           // 1600000
  const int* src = ei;
  const int* dst = ei + E;

  char* wsb = (char*)d_ws;
  size_t off = 0;
  auto alloc = [&](size_t bytes) -> void* {
    off = (off + 255) & ~(size_t)255;
    void* p = wsb + off;
    off += bytes;
    return p;
  };
  const int NREG = (E + 1023) / 1024;  // 1563 staging regions
  const int SHSZ = (E + 7) / 8;        // 200000: shard window (800KB of edges)
  int*   flag     = (int*)  alloc(16);
  float* dinv     = (float*)alloc((size_t)N * 4);
  int*   cnt      = (int*)  alloc((size_t)N * 4);
  int*   rowptr   = (int*)  alloc((size_t)(N + 1) * 4);
  u64*   sbasePk  = (u64*)  alloc((size_t)N * 8);
  uint4* nodeF    = (uint4*)alloc((size_t)N * 16);
  float2* dc      = (float2*)alloc((size_t)N * 8);
  int2*   rc      = (int2*) alloc((size_t)N * 8);
  int*   bsum     = (int*)  alloc(512 * 4);
  int*   boffs    = (int*)  alloc(512 * 4);
  float* v        = (float*)alloc(128 * 4);
  int*   histE    = (int*)  alloc((size_t)NREG * 8 * 4);
  unsigned short* W1T = (unsigned short*)alloc(128 * 128 * 2);
  float* cfac8    = (float*)alloc((size_t)N * 8 * 4);
  unsigned* edges = (unsigned*)alloc((size_t)E * 4);
  // regionA: {dc8 (N*8*8, dead after k_dinv) | rank (E*2, dead after fillA)}
  char* regionA = (char*)alloc((size_t)N * 8 * 8 + (size_t)E * 2);
  u64*            dc8  = (u64*)regionA;
  unsigned short* rank = (unsigned short*)(regionA + (size_t)N * 8 * 8);
  // regionB: stag (NREG*1024*8, dead after fillB) overlaid by H (N*128, from k_gemm)
  size_t stag_b = (size_t)NREG * 1024 * 8;
  size_t H_b    = (size_t)N * 128;
  char* regionB = (char*)alloc(stag_b > H_b ? stag_b : H_b);
  uint2*         stag = (uint2*)regionB;
  unsigned char* H    = (unsigned char*)regionB;
  (void)ws_size; (void)n_in; (void)out_size;

  const int nb_n  = (N + 255) / 256;   // 391
  const int nb_e4 = (E + 1023) / 1024; // 1563

  k_init<<<nb_n, 256, 0, stream>>>((const unsigned*)x, flag, dc8, cfac8, v, N);
  k_pass1<<<nb_e4, 256, 0, stream>>>(dst, w, dc8, rank, E, N, flag);
  k_dinv<<<nb_n, 256, 0, stream>>>(dc8, dinv, cnt, sbasePk, N);
  k_scanA<<<nb_n, 256, 0, stream>>>(cnt, rowptr, bsum, N);
  k_scanB<<<1, 512, 0, stream>>>(bsum, boffs, nb_n);
  k_scanC<<<nb_n, 256, 0, stream>>>(rowptr, boffs, sbasePk, dinv, nodeF, N);
  k_fillA<<<NREG, 256, 0, stream>>>(src, dst, w, nodeF, rank,
                                    stag, histE, cfac8, E, N, SHSZ, flag);
  k_fillB<<<((NREG + 3) / 4) * 8, 256, 0, stream>>>(stag, histE, edges, NREG);
  k_cfacm<<<nb_n, 256, 0, stream>>>(cfac8, dinv, rowptr, cnt, dc, rc, N);
  k_transpose<<<64, 256, 0, stream>>>(W1, W1T, flag);
  const int nwaves = (N + 15) / 16;
  const int nb_g = (nwaves + 3) / 4;
  k_gemm<<<nb_g, 256, 0, stream>>>(x, (const __bf16*)W1T, dinv, H, N, flag);
  const int nb_agg = 2048;
  k_agg<<<nb_agg, 256, 0, stream>>>(H, rc, dc, edges, b1, v, N, nb_agg, flag);
  k_head<<<1, 128, 0, stream>>>(v, W2, b2, Wmu, bmu, Wlv, blv,
                                d_out, 1.0f / (float)N, flag);
}

// Round 8
// 386.540 us; speedup vs baseline: 1.4309x; 1.0678x over previous
//
#include <hip/hip_runtime.h>

// SpectralGNNEncoder on MI355X.
// out = (mu, logvar):
//   h1 = relu(Agg1(x@W1) + b1)   (sym-norm scatter-add w/ self loops)
//   g  = mean(Agg2(h1@W2)) + b2 = ((1/N) c^T h1) @ W2 + b2,  c[i]=dinv[i]^2+dinv[i]*S[i]
// Round 8: global atomics write through to HBM (~30B/op) => eliminate the 1.6M cfac
// atomics: fillA emits a 2nd record stream (src|cfv) partitioned by src-shard; k_cfacB
// LDS-accumulates per-shard partials (atomic-free global); pass1 shadow -> blockIdx&7.

typedef __bf16 bf16x8 __attribute__((ext_vector_type(8)));
typedef float f32x4 __attribute__((ext_vector_type(4)));
typedef float f32x2 __attribute__((ext_vector_type(2)));
typedef unsigned long long u64;

__device__ __forceinline__ float bf2f(unsigned short u){
  return __uint_as_float(((unsigned)u) << 16);
}
__device__ __forceinline__ unsigned short f2bf(float f){
  unsigned u = __float_as_uint(f);
  u += 0x7fffu + ((u >> 16) & 1u);   // RNE
  return (unsigned short)(u >> 16);
}
__device__ __forceinline__ __bf16 us2bf(unsigned short u){
  __bf16 b; __builtin_memcpy(&b, &u, 2); return b;
}
__device__ __forceinline__ float ldf(const void* p, int i, int isf32){
  return isf32 ? ((const float*)p)[i] : bf2f(((const unsigned short*)p)[i]);
}
// fma 8 fp8 feats (packed in uint2) into acc[8]
__device__ __forceinline__ void fma8f8(float* acc, float n, uint2 h){
  f32x2 p0 = __builtin_amdgcn_cvt_pk_f32_fp8((int)h.x, false);
  f32x2 p1 = __builtin_amdgcn_cvt_pk_f32_fp8((int)h.x, true);
  f32x2 p2 = __builtin_amdgcn_cvt_pk_f32_fp8((int)h.y, false);
  f32x2 p3 = __builtin_amdgcn_cvt_pk_f32_fp8((int)h.y, true);
  acc[0] = fmaf(n, p0[0], acc[0]);
  acc[1] = fmaf(n, p0[1], acc[1]);
  acc[2] = fmaf(n, p1[0], acc[2]);
  acc[3] = fmaf(n, p1[1], acc[3]);
  acc[4] = fmaf(n, p2[0], acc[4]);
  acc[5] = fmaf(n, p2[1], acc[5]);
  acc[6] = fmaf(n, p3[0], acc[6]);
  acc[7] = fmaf(n, p3[1], acc[7]);
}

// ---------- init (+ dtype sniff in block 0): flag=1 iff float tensors are f32 ----------
__global__ void k_init(const unsigned* __restrict__ xw, int* __restrict__ flag,
                       u64* __restrict__ dc8, float* __restrict__ v, int N){
  int i = blockIdx.x * 256 + threadIdx.x;
  if (i < N){
    #pragma unroll
    for (int b = 0; b < 8; ++b) dc8[(size_t)b * N + i] = 0ull;
  }
  if (i < 128) v[i] = 0.0f;
  if (blockIdx.x == 0){
    __shared__ int s[256];
    int t = threadIdx.x;
    int cnt = 0;
    for (int k = t; k < 4096; k += 256){
      unsigned lo = xw[k] & 0xFFFFu;
      int e = (int)((lo >> 7) & 0xFFu);
      if ((e >= 100 && e <= 141) || (lo & 0x7FFFu) == 0) cnt++;
    }
    s[t] = cnt;
    __syncthreads();
    for (int off = 128; off > 0; off >>= 1){
      if (t < off) s[t] += s[t + off];
      __syncthreads();
    }
    if (t == 0) *flag = (s[0] < 2458) ? 1 : 0;
  }
}

// ---------- pass1: u64 atomic = deg(fixed)|cnt, rank from old; shadow = blockIdx&7 ----------
__global__ void __launch_bounds__(256) k_pass1(const int* __restrict__ dst,
                        const void* __restrict__ w,
                        u64* __restrict__ dc8, unsigned short* __restrict__ rank,
                        int E, int N, const int* __restrict__ flagp){
  int isf32 = *flagp;
  int tid = threadIdx.x;
  int b = (int)blockIdx.x & 7;                     // XCD-local slab; MUST match fillA
  int ev[4]; int dv[4]; float wv[4];
  #pragma unroll
  for (int k = 0; k < 4; ++k){
    int e = blockIdx.x * 1024 + k * 256 + tid;
    ev[k] = e;
    dv[k] = (e < E) ? dst[e] : 0;
    wv[k] = (e < E) ? ldf(w, e, isf32) : 0.0f;
  }
  u64 old[4];
  #pragma unroll
  for (int k = 0; k < 4; ++k){
    if (ev[k] < E){
      u64 wfix = (u64)(wv[k] * 65536.0f + 0.5f);
      old[k] = atomicAdd(&dc8[(size_t)b * N + dv[k]], (1ull << 40) | wfix);
    }
  }
  #pragma unroll
  for (int k = 0; k < 4; ++k)
    if (ev[k] < E) rank[ev[k]] = (unsigned short)(old[k] >> 40);
}

// ---------- merge shadows: dinv, cnt, packed per-shadow prefix bytes ----------
__global__ void k_dinv(const u64* __restrict__ dc8, float* __restrict__ dinv,
                       int* __restrict__ cnt, u64* __restrict__ sbasePk, int N){
  int i = blockIdx.x * 256 + threadIdx.x;
  if (i >= N) return;
  unsigned sb = 0;
  u64 degfix = 0, pk = 0;
  #pragma unroll
  for (int b = 0; b < 8; ++b){
    u64 dcb = dc8[(size_t)b * N + i];
    pk |= ((u64)(sb & 0xFFu)) << (8 * b);          // exclusive prefix for shadow b
    sb += (unsigned)(dcb >> 40);
    degfix += dcb & 0xFFFFFFFFFFull;
  }
  float deg = 1.0f + (float)degfix * (1.0f / 65536.0f);  // +1 self loop
  dinv[i] = rsqrtf(deg);
  cnt[i] = (int)sb;
  sbasePk[i] = pk;
}

// ---------- exclusive scan of cnt -> rowptr ----------
__global__ void k_scanA(const int* __restrict__ cnt, int* __restrict__ rowptr,
                        int* __restrict__ bsum, int N){
  __shared__ int s[256];
  int i = blockIdx.x * 256 + threadIdx.x;
  int val = (i < N) ? cnt[i] : 0;
  s[threadIdx.x] = val;
  __syncthreads();
  for (int off = 1; off < 256; off <<= 1){
    int tmp = (threadIdx.x >= off) ? s[threadIdx.x - off] : 0;
    __syncthreads();
    s[threadIdx.x] += tmp;
    __syncthreads();
  }
  if (i < N) rowptr[i] = s[threadIdx.x] - val;
  if (threadIdx.x == 255) bsum[blockIdx.x] = s[255];
}

__global__ void k_scanB(const int* __restrict__ bsum, int* __restrict__ boffs, int NB){
  __shared__ int s[512];
  int t = threadIdx.x;
  int val = (t < NB) ? bsum[t] : 0;
  s[t] = val;
  __syncthreads();
  for (int off = 1; off < 512; off <<= 1){
    int tmp = (t >= off) ? s[t - off] : 0;
    __syncthreads();
    s[t] += tmp;
    __syncthreads();
  }
  boffs[t] = s[t] - val;
}

// ---------- scanC: finalize rowptr AND build nodeF = {sbasePk(8B), rowptr(4B), dinv(4B)} ----------
__global__ void k_scanC(int* __restrict__ rowptr, const int* __restrict__ boffs,
                        const u64* __restrict__ sbasePk, const float* __restrict__ dinv,
                        uint4* __restrict__ nodeF, int N){
  int i = blockIdx.x * 256 + threadIdx.x;
  if (i >= N) return;
  int rp = rowptr[i] + boffs[blockIdx.x];
  rowptr[i] = rp;
  u64 pk = sbasePk[i];
  uint4 nf;
  nf.x = (unsigned)(pk & 0xFFFFFFFFull);
  nf.y = (unsigned)(pk >> 32);
  nf.z = (unsigned)rp;
  nf.w = __float_as_uint(dinv[i]);
  nodeF[i] = nf;
}

// ---------- fillA: two record streams, one combined 256-group LDS partition.
// stream1: (pos, src|wq) by pos-shard (edges scatter); stream2: (src|cfv) by src-shard.
// NO global atomics. ----------
__global__ void __launch_bounds__(256) k_fillA(const int* __restrict__ src,
    const int* __restrict__ dst, const void* __restrict__ w,
    const uint4* __restrict__ nodeF, const unsigned short* __restrict__ rank,
    uint2* __restrict__ stag, unsigned* __restrict__ stag2,
    int* __restrict__ histE, int* __restrict__ hist2,
    int E, int SHSZ, int SRCSH, const int* __restrict__ flagp){
  __shared__ int gcnt[256];
  __shared__ int gincl[256];
  __shared__ uint2 buf[1024];
  __shared__ unsigned buf2[1024];
  int tid = threadIdx.x, lane = tid & 63, wv = tid >> 6;
  gcnt[tid] = 0;
  __syncthreads();
  int isf32 = *flagp;
  u64 ltmask = (1ull << lane) - 1ull;
  int b = (int)blockIdx.x & 7;                     // shadow; MUST match k_pass1
  int sv[4]; float wq[4]; int rk[4]; int ev[4];
  uint4 nf[4];
  #pragma unroll
  for (int k = 0; k < 4; ++k){
    int e = blockIdx.x * 1024 + k * 256 + tid;
    ev[k] = e;
    int d_ = 0;
    if (e < E){
      sv[k] = src[e];
      d_    = dst[e];
      wq[k] = ldf(w, e, isf32);
      rk[k] = rank[e];
    } else { sv[k] = 0; wq[k] = 0.0f; rk[k] = 0; }
    nf[k] = nodeF[d_];
  }
  int shv[4], offv[4], sh2v[4], off2v[4];
  unsigned posv[4], valv[4], val2v[4];
  #pragma unroll
  for (int k = 0; k < 4; ++k){
    int sh = -1, sh2 = -1; unsigned pos = 0, val = 0, val2 = 0;
    if (ev[k] < E){
      u64 pk = ((u64)nf[k].y << 32) | nf[k].x;
      unsigned sb = (unsigned)((pk >> (8 * b)) & 0xFFu);
      int p = (int)nf[k].z + (int)sb + rk[k];
      if (p >= E) p = E - 1;                       // safety clamp
      int nq = (int)(wq[k] * 32768.0f + 0.5f);
      if (nq > 32767) nq = 32767;
      pos = (unsigned)p;
      val = ((unsigned)sv[k] << 15) | (unsigned)nq;
      sh = (int)(pos / (unsigned)SHSZ);
      float cfv = wq[k] * __uint_as_float(nf[k].w);    // w_e * dinv_dst
      int nq2 = (int)(cfv * 32768.0f + 0.5f);
      if (nq2 > 32767) nq2 = 32767;
      val2 = ((unsigned)sv[k] << 15) | (unsigned)nq2;
      sh2 = sv[k] / SRCSH;
    }
    int myoff = 0, myoff2 = 0;
    #pragma unroll
    for (int s = 0; s < 8; ++s){
      u64 m = __ballot(sh == s);
      if (sh == s){
        myoff = __popcll(m & ltmask);
        if (myoff == 0) gcnt[s * 16 + k * 4 + wv] = __popcll(m);
      }
      u64 m2 = __ballot(sh2 == s);
      if (sh2 == s){
        myoff2 = __popcll(m2 & ltmask);
        if (myoff2 == 0) gcnt[128 + s * 16 + k * 4 + wv] = __popcll(m2);
      }
    }
    shv[k] = sh; offv[k] = myoff; posv[k] = pos; valv[k] = val;
    sh2v[k] = sh2; off2v[k] = myoff2; val2v[k] = val2;
  }
  __syncthreads();
  gincl[tid] = gcnt[tid];
  __syncthreads();
  for (int ofs = 1; ofs < 256; ofs <<= 1){
    int t2 = (tid >= ofs) ? gincl[tid - ofs] : 0;
    __syncthreads();
    gincl[tid] += t2;
    __syncthreads();
  }
  int tot1 = gincl[127];
  #pragma unroll
  for (int k = 0; k < 4; ++k){
    if (shv[k] >= 0){
      int idx = shv[k] * 16 + k * 4 + wv;
      buf[gincl[idx] - gcnt[idx] + offv[k]] = make_uint2(posv[k], valv[k]);
      int idx2 = 128 + sh2v[k] * 16 + k * 4 + wv;
      buf2[gincl[idx2] - gcnt[idx2] - tot1 + off2v[k]] = val2v[k];
    }
  }
  __syncthreads();
  for (int t = tid; t < tot1; t += 256)
    stag[(size_t)blockIdx.x * 1024 + t] = buf[t];
  int tot2 = gincl[255] - tot1;
  for (int t = tid; t < tot2; t += 256)
    stag2[(size_t)blockIdx.x * 1024 + t] = buf2[t];
  if (tid < 8){
    int a  = gincl[tid * 16 + 15];
    int pr = tid ? gincl[tid * 16 - 1] : 0;
    histE[blockIdx.x * 8 + tid] = a - pr;
    int a2  = gincl[128 + tid * 16 + 15];
    int pr2 = gincl[128 + tid * 16 - 1];           // tid=0 -> gincl[127]=tot1
    hist2[blockIdx.x * 8 + tid] = a2 - pr2;
  }
}

// ---------- fillB: STATIC assignment. Block B -> shard s=B&7 (XCD-pinned),
// regions (B>>3)*4 + wave. No atomics, no spins. ----------
__global__ void __launch_bounds__(256) k_fillB(const uint2* __restrict__ stag,
    const int* __restrict__ histE, unsigned* __restrict__ edges, int NREG){
  int tid = threadIdx.x, lane = tid & 63, wv = tid >> 6;
  int s = (int)blockIdx.x & 7;
  int r = ((int)blockIdx.x >> 3) * 4 + wv;
  if (r >= NREG) return;
  int hv = (lane < 8) ? histE[r * 8 + lane] : 0;
  int off = 0, len = 0;
  #pragma unroll
  for (int i = 0; i < 8; ++i){
    int h = __shfl(hv, i);
    if (i < s) off += h;
    if (i == s) len = h;
  }
  const uint2* rp = stag + (size_t)r * 1024 + off;
  for (int i = lane; i < len; i += 64){
    uint2 rec = rp[i];
    edges[rec.x] = rec.y;                          // scatter into L2-local 800KB window
  }
}

// ---------- cfacB: block (s=B&7, j=B>>3 of 16): LDS-accumulate shard s's records
// from regions [j*per, ...), write dense partial. Atomic-free in global. ----------
__global__ void __launch_bounds__(256) k_cfacB(const unsigned* __restrict__ stag2,
    const int* __restrict__ hist2, float* __restrict__ cfacP, int NREG, int SRCSH){
  __shared__ float acc[12544];
  int tid = threadIdx.x, lane = tid & 63, wv = tid >> 6;
  int s = (int)blockIdx.x & 7;
  int j = (int)blockIdx.x >> 3;                    // 0..15
  for (int i = tid; i < 12544; i += 256) acc[i] = 0.0f;
  __syncthreads();
  int base = s * SRCSH;
  int per = (NREG + 15) / 16;
  int r0 = j * per, r1 = r0 + per;
  if (r1 > NREG) r1 = NREG;
  for (int r = r0 + wv; r < r1; r += 4){           // each wave owns its regions
    int hv = (lane < 8) ? hist2[r * 8 + lane] : 0;
    int off = 0, len = 0;
    #pragma unroll
    for (int i = 0; i < 8; ++i){
      int h = __shfl(hv, i);
      if (i < s) off += h;
      if (i == s) len = h;
    }
    const unsigned* rp = stag2 + (size_t)r * 1024 + off;
    for (int i = lane; i < len; i += 64){
      unsigned rec = rp[i];
      atomicAdd(&acc[(int)(rec >> 15) - base], (float)(rec & 32767u) * (1.0f / 32768.0f));
    }
  }
  __syncthreads();
  float* op = cfacP + (size_t)blockIdx.x * SRCSH;
  for (int i = tid; i < SRCSH; i += 256) op[i] = acc[i];
}

// ---------- cfacm: sum 16 partials; pack (dinv, cfac) and (rowptr, cnt) ----------
__global__ void k_cfacm(const float* __restrict__ cfacP, const float* __restrict__ dinv,
                        const int* __restrict__ rowptr, const int* __restrict__ cnt,
                        float2* __restrict__ dc, int2* __restrict__ rc, int N, int SRCSH){
  int i = blockIdx.x * 256 + threadIdx.x;
  if (i >= N) return;
  int s = i / SRCSH, ii = i - s * SRCSH;
  float S = 0.0f;
  #pragma unroll
  for (int j = 0; j < 16; ++j)
    S += cfacP[(size_t)(j * 8 + s) * SRCSH + ii];
  float di = dinv[i];
  dc[i] = make_float2(di, di * di + di * S);       // (dinv, cfac)
  rc[i] = make_int2(rowptr[i], cnt[i]);
}

// ---------- W1T[n*128+k] = W1[k*128+n], canonical bf16 ----------
__global__ void k_transpose(const void* __restrict__ W1, unsigned short* __restrict__ W1T,
                            const int* __restrict__ flagp){
  int gid = blockIdx.x * 256 + threadIdx.x;
  int isf32 = *flagp;
  int k = gid & 127, n = gid >> 7;
  W1T[gid] = isf32 ? f2bf(((const float*)W1)[k * 128 + n])
                   : ((const unsigned short*)W1)[k * 128 + n];
}

// ---------- H' = 8*dinv_row*(x@W1) as fp8, 4 feature-planes of 32 ----------
__global__ void __launch_bounds__(256) k_gemm(const void* __restrict__ xv,
                                              const __bf16* __restrict__ wt,
                                              const float* __restrict__ dinv,
                                              unsigned char* __restrict__ H, int N,
                                              const int* __restrict__ flagp){
  int wave = (blockIdx.x * blockDim.x + threadIdx.x) >> 6;
  int lane = threadIdx.x & 63;
  int row16 = wave << 4;
  if (row16 >= N) return;
  int isf32 = *flagp;
  int m = lane & 15, q = lane >> 4;
  size_t planeStride = (size_t)N * 32;
  f32x4 dv;
  {
    const float4 d4 = *(const float4*)(dinv + row16 + q * 4);
    dv[0] = 8.0f * d4.x; dv[1] = 8.0f * d4.y; dv[2] = 8.0f * d4.z; dv[3] = 8.0f * d4.w;
  }
  bf16x8 a0, a1, a2, a3;
  if (isf32){
    const float* ap = (const float*)xv + (size_t)(row16 + m) * 128 + q * 8;
    #pragma unroll
    for (int j = 0; j < 8; ++j){
      a0[j] = us2bf(f2bf(ap[j +  0]));
      a1[j] = us2bf(f2bf(ap[j + 32]));
      a2[j] = us2bf(f2bf(ap[j + 64]));
      a3[j] = us2bf(f2bf(ap[j + 96]));
    }
  } else {
    const __bf16* ap = (const __bf16*)xv + (size_t)(row16 + m) * 128 + q * 8;
    a0 = *(const bf16x8*)(ap +  0);
    a1 = *(const bf16x8*)(ap + 32);
    a2 = *(const bf16x8*)(ap + 64);
    a3 = *(const bf16x8*)(ap + 96);
  }
  for (int nt = 0; nt < 8; ++nt){
    const __bf16* bp = wt + (size_t)(nt * 16 + m) * 128 + q * 8;
    bf16x8 b0 = *(const bf16x8*)(bp +  0);
    bf16x8 b1 = *(const bf16x8*)(bp + 32);
    bf16x8 b2 = *(const bf16x8*)(bp + 64);
    bf16x8 b3 = *(const bf16x8*)(bp + 96);
    f32x4 acc = {0.f, 0.f, 0.f, 0.f};
    acc = __builtin_amdgcn_mfma_f32_16x16x32_bf16(a0, b0, acc, 0, 0, 0);
    acc = __builtin_amdgcn_mfma_f32_16x16x32_bf16(a1, b1, acc, 0, 0, 0);
    acc = __builtin_amdgcn_mfma_f32_16x16x32_bf16(a2, b2, acc, 0, 0, 0);
    acc = __builtin_amdgcn_mfma_f32_16x16x32_bf16(a3, b3, acc, 0, 0, 0);
    unsigned char* op = H + (size_t)(nt >> 1) * planeStride
                          + (size_t)(row16 + q * 4) * 32 + (nt & 1) * 16 + m;
    float v0 = acc[0] * dv[0], v1 = acc[1] * dv[1];
    float v2 = acc[2] * dv[2], v3 = acc[3] * dv[3];
    op[0]  = (unsigned char)(__builtin_amdgcn_cvt_pk_fp8_f32(v0, v0, 0, false) & 0xFF);
    op[32] = (unsigned char)(__builtin_amdgcn_cvt_pk_fp8_f32(v1, v1, 0, false) & 0xFF);
    op[64] = (unsigned char)(__builtin_amdgcn_cvt_pk_fp8_f32(v2, v2, 0, false) & 0xFF);
    op[96] = (unsigned char)(__builtin_amdgcn_cvt_pk_fp8_f32(v3, v3, 0, false) & 0xFF);
  }
}

// ---------- k_agg: XCD-sliced slot-parallel gather; 2-deep pipeline ----------
__global__ void __launch_bounds__(256) k_agg(const unsigned char* __restrict__ H,
    const int2* __restrict__ rc, const float2* __restrict__ dc,
    const unsigned* __restrict__ edges, const void* __restrict__ b1,
    float* __restrict__ v, int N, int nblk, const int* __restrict__ flagp){
  __shared__ float vsh[32];
  int tid = threadIdx.x;
  if (tid < 32) vsh[tid] = 0.0f;
  __syncthreads();
  int isf32 = *flagp;
  int lane = tid & 63;
  int wv = tid >> 6;                  // wave in block 0..3
  int slot = lane >> 2;               // 0..15
  int q = lane & 3;                   // feature quarter within slice
  int sl = (blockIdx.x & 7) >> 1;     // slice/plane 0..3
  int jblk = (int)(blockIdx.x >> 3) * 2 + (blockIdx.x & 1);   // rank within slice
  int slotg = (jblk * 4 + wv) * 16 + slot;
  int totslots = (nblk >> 3) * 2 * 4 * 16;
  const unsigned char* Hp = H + (size_t)sl * ((size_t)N * 32);
  int fbase = sl * 32 + q * 8;
  float bx[8];
  #pragma unroll
  for (int j = 0; j < 8; ++j) bx[j] = ldf(b1, fbase + j, isf32);
  float ax[8] = {0,0,0,0,0,0,0,0};
  for (int d = slotg; d < N; d += totslots){
    int2  rcv = rc[d];                 // (rowptr, cnt)
    float2 dcv = dc[d];                // (dinv, cfac)
    float acc[8] = {0,0,0,0,0,0,0,0};
    uint2 hs = *(const uint2*)(Hp + (size_t)d * 32 + q * 8);
    fma8f8(acc, 1.0f, hs);             // self-loop: weight 1 in H' space
    int p = rcv.x, pe = rcv.x + rcv.y;
    if (p < pe){
      unsigned r = edges[p];
      uint2 h = *(const uint2*)(Hp + (size_t)(r >> 15) * 32 + q * 8);
      while (++p < pe){
        unsigned rn = edges[p];        // next edge word in flight
        uint2 hn = *(const uint2*)(Hp + (size_t)(rn >> 15) * 32 + q * 8);  // next gather
        fma8f8(acc, (float)(r & 32767u) * (1.0f / 32768.0f), h);
        r = rn; h = hn;
      }
      fma8f8(acc, (float)(r & 32767u) * (1.0f / 32768.0f), h);
    }
    float scale = dcv.x * 0.125f;      // dinv_d / 8
    #pragma unroll
    for (int j = 0; j < 8; ++j){
      float rj = fmaxf(fmaf(scale, acc[j], bx[j]), 0.0f);
      ax[j] = fmaf(dcv.y, rj, ax[j]);
    }
  }
  // cross-slot reduce (lane bits 2..5), once per wave
  #pragma unroll
  for (int j = 0; j < 8; ++j){
    ax[j] += __shfl_xor(ax[j], 4);
    ax[j] += __shfl_xor(ax[j], 8);
    ax[j] += __shfl_xor(ax[j], 16);
    ax[j] += __shfl_xor(ax[j], 32);
  }
  if (slot == 0){
    #pragma unroll
    for (int j = 0; j < 8; ++j) atomicAdd(&vsh[q * 8 + j], ax[j]);
  }
  __syncthreads();
  if (tid < 32) atomicAdd(&v[sl * 32 + tid], vsh[tid]);
}

// ---------- tiny head ----------
__global__ void __launch_bounds__(128) k_head(const float* __restrict__ v,
    const void* __restrict__ W2, const void* __restrict__ b2,
    const void* __restrict__ Wmu, const void* __restrict__ bmu,
    const void* __restrict__ Wlv, const void* __restrict__ blv,
    void* __restrict__ outv, float invN, const int* __restrict__ flagp){
  __shared__ float gsh[128];
  __shared__ float tsh[128];
  int t = threadIdx.x;
  int isf32 = *flagp;
  gsh[t] = v[t] * invN;
  __syncthreads();
  float acc = ldf(b2, t, isf32);
  for (int k = 0; k < 128; ++k) acc = fmaf(gsh[k], ldf(W2, k * 128 + t, isf32), acc);
  tsh[t] = acc;
  __syncthreads();
  int j = t & 63;
  const void* Wp = (t < 64) ? Wmu : Wlv;
  float o = ldf((t < 64) ? bmu : blv, j, isf32);
  for (int k = 0; k < 128; ++k) o = fmaf(tsh[k], ldf(Wp, k * 64 + j, isf32), o);
  if (isf32) ((float*)outv)[t] = o;
  else       ((unsigned short*)outv)[t] = f2bf(o);
}

extern "C" void kernel_launch(void* const* d_in, const int* in_sizes, int n_in,
                              void* d_out, int out_size, void* d_ws, size_t ws_size,
                              hipStream_t stream) {
  const void* x   = d_in[0];
  const int*  ei  = (const int*)d_in[1];
  const void* w   = d_in[2];
  const void* W1  = d_in[3];
  const void* b1  = d_in[4];
  const void* W2  = d_in[5];
  const void* b2  = d_in[6];
  const void* Wmu = d_in[7];
  const void* bmu = d_in[8];
  const void* Wlv = d_in[9];
  const void* blv = d_in[10];

  const int N = in_sizes[0] / 128;     // 100000
  const int E = in_sizes[2];           // 1600000
  const int* src = ei;
  const int* dst = ei + E;

  char* wsb = (char*)d_ws;
  size_t off = 0;
  auto alloc = [&](size_t bytes) -> void* {
    off = (off + 255) & ~(size_t)255;
    void* p = wsb + off;
    off += bytes;
    return p;
  };
  const int NREG  = (E + 1023) / 1024; // 1563 regions
  const int SHSZ  = (E + 7) / 8;       // 200000: pos-shard window (800KB of edges)
  const int SRCSH = (N + 7) / 8;       // 12500: src-shard width (<=12544 LDS)
  int*   flag     = (int*)  alloc(16);
  float* dinv     = (float*)alloc((size_t)N * 4);
  int*   cnt      = (int*)  alloc((size_t)N * 4);
  int*   rowptr   = (int*)  alloc((size_t)(N + 1) * 4);
  u64*   sbasePk  = (u64*)  alloc((size_t)N * 8);
  uint4* nodeF    = (uint4*)alloc((size_t)N * 16);
  float2* dc      = (float2*)alloc((size_t)N * 8);
  int2*   rc      = (int2*) alloc((size_t)N * 8);
  int*   bsum     = (int*)  alloc(512 * 4);
  int*   boffs    = (int*)  alloc(512 * 4);
  float* v        = (float*)alloc(128 * 4);
  int*   histE    = (int*)  alloc((size_t)NREG * 8 * 4);
  int*   hist2    = (int*)  alloc((size_t)NREG * 8 * 4);
  unsigned short* W1T = (unsigned short*)alloc(128 * 128 * 2);
  float* cfacP    = (float*)alloc((size_t)128 * SRCSH * 4);   // 16 partials x 8 shards
  unsigned* edges = (unsigned*)alloc((size_t)E * 4);
  // regionA: [0, stag2_b): dc8 (N*8*8, dead after k_dinv) overlaid by stag2
  // (NREG*1024*4, written by fillA); rank (E*2) after, read by fillA only.
  size_t dc8_b   = (size_t)N * 8 * 8;
  size_t stag2_b = (size_t)NREG * 1024 * 4;
  size_t ovl     = dc8_b > stag2_b ? dc8_b : stag2_b;
  char* regionA = (char*)alloc(ovl + (size_t)E * 2);
  u64*            dc8   = (u64*)regionA;
  unsigned*       stag2 = (unsigned*)regionA;
  unsigned short* rank  = (unsigned short*)(regionA + ovl);
  // regionB: stag (NREG*1024*8, dead after fillB) overlaid by H (N*128, from k_gemm)
  size_t stag_b = (size_t)NREG * 1024 * 8;
  size_t H_b    = (size_t)N * 128;
  char* regionB = (char*)alloc(stag_b > H_b ? stag_b : H_b);
  uint2*         stag = (uint2*)regionB;
  unsigned char* H    = (unsigned char*)regionB;
  (void)ws_size; (void)n_in; (void)out_size;

  const int nb_n  = (N + 255) / 256;   // 391

  k_init<<<nb_n, 256, 0, stream>>>((const unsigned*)x, flag, dc8, v, N);
  k_pass1<<<NREG, 256, 0, stream>>>(dst, w, dc8, rank, E, N, flag);
  k_dinv<<<nb_n, 256, 0, stream>>>(dc8, dinv, cnt, sbasePk, N);
  k_scanA<<<nb_n, 256, 0, stream>>>(cnt, rowptr, bsum, N);
  k_scanB<<<1, 512, 0, stream>>>(bsum, boffs, nb_n);
  k_scanC<<<nb_n, 256, 0, stream>>>(rowptr, boffs, sbasePk, dinv, nodeF, N);
  k_fillA<<<NREG, 256, 0, stream>>>(src, dst, w, nodeF, rank,
                                    stag, stag2, histE, hist2, E, SHSZ, SRCSH, flag);
  k_fillB<<<((NREG + 3) / 4) * 8, 256, 0, stream>>>(stag, histE, edges, NREG);
  k_cfacB<<<128, 256, 0, stream>>>(stag2, hist2, cfacP, NREG, SRCSH);
  k_cfacm<<<nb_n, 256, 0, stream>>>(cfacP, dinv, rowptr, cnt, dc, rc, N, SRCSH);
  k_transpose<<<64, 256, 0, stream>>>(W1, W1T, flag);
  const int nwaves = (N + 15) / 16;
  const int nb_g = (nwaves + 3) / 4;
  k_gemm<<<nb_g, 256, 0, stream>>>(x, (const __bf16*)W1T, dinv, H, N, flag);
  const int nb_agg = 2048;
  k_agg<<<nb_agg, 256, 0, stream>>>(H, rc, dc, edges, b1, v, N, nb_agg, flag);
  k_head<<<1, 128, 0, stream>>>(v, W2, b2, Wmu, bmu, Wlv, blv,
                                d_out, 1.0f / (float)N, flag);
}